// Round 1
// baseline (13247.893 us; speedup 1.0000x reference)
//
#include <hip/hip_runtime.h>

// BiLSTM-CRF, f32-faithful. See header theory: recurrence = 128 independent
// (batch,dir) chains, one 1024-thread wg each, Whh in 256 VGPRs/thread,
// 2-level DPP quad reduce; xproj pipelined on the other 128 CUs; Viterbi
// per-batch single-wave scan with bps in LDS.

#define SLEN 512
#define NTAG 9
#define NEGV -10000.0f
#define MSZ (1024*256)

__device__ __forceinline__ float sigmf(float x){ return 1.0f/(1.0f+expf(-x)); }

// sum over the 4-lane quad (all 4 lanes receive the total)
__device__ __forceinline__ float quadsum(float v){
  int t = __builtin_amdgcn_update_dpp(0, __float_as_int(v), 0xB1, 0xF, 0xF, false); // quad_perm [1,0,3,2]
  v += __int_as_float(t);
  t = __builtin_amdgcn_update_dpp(0, __float_as_int(v), 0x4E, 0xF, 0xF, false);     // quad_perm [2,3,0,1]
  return v + __int_as_float(t);
}

// per-lane partial gemv: lane owns k-quarter q (64 k's), 4 gates (passes)
__device__ __forceinline__ void gemv4(const float (&w)[4][64], const float* __restrict__ sq,
                                      float &a0, float &a1, float &a2, float &a3){
  a0=0.f; a1=0.f; a2=0.f; a3=0.f;
  #pragma unroll
  for (int i=0;i<16;i++){
    float4 hv = *(const float4*)(sq + i*4);
    a0 = fmaf(hv.x, w[0][i*4+0], a0); a0 = fmaf(hv.y, w[0][i*4+1], a0);
    a0 = fmaf(hv.z, w[0][i*4+2], a0); a0 = fmaf(hv.w, w[0][i*4+3], a0);
    a1 = fmaf(hv.x, w[1][i*4+0], a1); a1 = fmaf(hv.y, w[1][i*4+1], a1);
    a1 = fmaf(hv.z, w[1][i*4+2], a1); a1 = fmaf(hv.w, w[1][i*4+3], a1);
    a2 = fmaf(hv.x, w[2][i*4+0], a2); a2 = fmaf(hv.y, w[2][i*4+1], a2);
    a2 = fmaf(hv.z, w[2][i*4+2], a2); a2 = fmaf(hv.w, w[2][i*4+3], a2);
    a3 = fmaf(hv.x, w[3][i*4+0], a3); a3 = fmaf(hv.y, w[3][i*4+1], a3);
    a3 = fmaf(hv.z, w[3][i*4+2], a3); a3 = fmaf(hv.w, w[3][i*4+3], a3);
  }
}

// Swizzle W [1024][256] so the per-lane weight loads are coalesced dwordx4.
// wswz layout (per matrix): idx = (((wave*4+p)*16+i)*64 + lane)*4 + e
//   -> W[n][k], n = wave*64+p*16+(lane>>2), k = (lane&3)*64 + i*4 + e
__global__ void prep_swz(const float* __restrict__ wih_f, const float* __restrict__ whh_f,
                         const float* __restrict__ wih_r, const float* __restrict__ whh_r,
                         float* __restrict__ out){
  for (long idx = blockIdx.x*(long)blockDim.x + threadIdx.x; idx < 4l*MSZ;
       idx += (long)gridDim.x*blockDim.x){
    int m = (int)(idx >> 18);
    int o = (int)(idx & (MSZ-1));
    int e = o & 3, L = (o>>2)&63, i = (o>>8)&15, p = (o>>12)&3, w = o>>14;
    int n = w*64 + p*16 + (L>>2);
    int k = (L&3)*64 + i*4 + e;
    const float* s = (m==0)?wih_f:(m==1)?wih_r:(m==2)?whh_f:whh_r;
    out[idx] = s[n*256 + k];
  }
}

// Roles per launch Lx (chunk size Sc, C = 512/Sc chunks):
//   Lx==0            : all 256 wgs do xproj(chunk 0), split halves
//   Lx in [1..C+1]   : wg<128 -> recurrence(chunk Lx-1) ; wg>=128 -> xproj(Lx) + feats(Lx-2)
__global__ __launch_bounds__(1024) void bilstm_main(
    int Lx, int C, int Sc,
    const int*   __restrict__ ids,     // [64][512]
    const float* __restrict__ embed,   // [V][256]
    const float* __restrict__ wswz,    // [role*2+dir][1024*256]  role0=Wih,1=Whh
    const float* __restrict__ bias_f, const float* __restrict__ bias_r,
    const float* __restrict__ wout,    // [9][512]
    float* __restrict__ xg, long xg_str,   // dbuf [2][2][Sc][64][1024]
    float* __restrict__ hs, long hs_str,   // dbuf [2][2][Sc][64][256]
    float* __restrict__ feats,             // [512][64][9]
    float* __restrict__ st_h, float* __restrict__ st_c) // [2][64][256]
{
  __shared__ float src_lds[4*68];     // h or x, quarter-padded (bank-conflict-free)
  __shared__ float gates_lds[1024];

  const int tid = threadIdx.x;
  const int wave = tid>>6, lane = tid&63, q = lane&3, g = lane>>2;
  const int wgid = blockIdx.x;

  bool do_recur=false, do_xproj=false, do_feats=false;
  int d=0, b=0, sp0=0, sp1=Sc, cr=0, cx=0, cf=-1;
  if (Lx == 0){
    d = (wgid>>6)&1; b = wgid&63;
    do_xproj = true; cx = 0;
    sp0 = (wgid>>7) ? (Sc/2) : 0;
    sp1 = (wgid>>7) ? Sc : (Sc/2);
  } else if (wgid < 128){
    d = wgid>>6; b = wgid&63;
    cr = Lx-1; do_recur = (cr < C);
  } else {
    int w2 = wgid-128; d = w2>>6; b = w2&63;
    cx = Lx; do_xproj = (cx < C);
    cf = Lx-2; do_feats = (cf >= 0 && cf < C);
  }

  float w[4][64];   // 256 VGPRs of resident weights (static-indexed only!)
  if (do_recur || do_xproj){
    int role = do_recur ? 1 : 0;
    const float4* wp = (const float4*)(wswz + (long)(role*2 + d)*MSZ);
    #pragma unroll
    for (int p=0;p<4;p++){
      #pragma unroll
      for (int i=0;i<16;i++){
        float4 v = wp[((wave*4+p)*16 + i)*64 + lane];
        w[p][i*4+0]=v.x; w[p][i*4+1]=v.y; w[p][i*4+2]=v.z; w[p][i*4+3]=v.w;
      }
    }
  }

  if (do_recur){
    const float* xgr = xg + ((long)(cr&1))*xg_str + (long)d*Sc*65536;
    float*       hsw = hs + ((long)(cr&1))*hs_str + (long)d*Sc*16384;
    const int*  idsb = ids + b*SLEN;
    float h_reg=0.f, c_reg=0.f;
    if (tid < 256){
      h_reg = st_h[(d*64+b)*256 + tid];
      c_reg = st_c[(d*64+b)*256 + tid];
      src_lds[(tid>>6)*68 + (tid&63)] = h_reg;
    }
    __syncthreads();
    for (int sp=0; sp<Sc; sp++){
      const int sg = (d==0) ? (cr*Sc + sp) : (SLEN-1 - cr*Sc - sp);
      float xgi=0,xgf=0,xgg=0,xgo=0; int idv=0;
      if (tid < 256){
        const float* xr = xgr + (long)sp*65536 + b*1024 + tid;
        xgi = xr[0]; xgf = xr[256]; xgg = xr[512]; xgo = xr[768];
        idv = idsb[sg];                  // mask == (id != 0) by construction
      }
      float a0,a1,a2,a3;
      gemv4(w, src_lds + q*68, a0,a1,a2,a3);
      a0 = quadsum(a0); a1 = quadsum(a1); a2 = quadsum(a2); a3 = quadsum(a3);
      if (q == 0){
        int nb = wave*64 + g;
        gates_lds[nb]    = a0; gates_lds[nb+16] = a1;
        gates_lds[nb+32] = a2; gates_lds[nb+48] = a3;
      }
      __syncthreads();
      if (tid < 256){
        float pi = xgi + gates_lds[tid];
        float pf = xgf + gates_lds[256+tid];
        float pg = xgg + gates_lds[512+tid];
        float po = xgo + gates_lds[768+tid];
        float ii=sigmf(pi), ff=sigmf(pf), gv=tanhf(pg), oo=sigmf(po);
        float cn = ff*c_reg + ii*gv;
        float hn = oo*tanhf(cn);
        if (idv != 0){ c_reg = cn; h_reg = hn; }     // freeze on masked steps
        src_lds[(tid>>6)*68 + (tid&63)] = h_reg;
        hsw[(long)sp*16384 + b*256 + tid] = h_reg;
      }
      __syncthreads();
    }
    if (tid < 256){
      st_h[(d*64+b)*256+tid] = h_reg;
      st_c[(d*64+b)*256+tid] = c_reg;
    }
  }

  if (do_xproj){
    float*      xgw = xg + ((long)(cx&1))*xg_str + (long)d*Sc*65536;
    const int* idsb = ids + b*SLEN;
    const float* bptr = (d==0)? bias_f : bias_r;
    float bb0=0,bb1=0,bb2=0,bb3=0;
    if (q==0){
      int nb = wave*64 + g;
      bb0=bptr[nb]; bb1=bptr[nb+16]; bb2=bptr[nb+32]; bb3=bptr[nb+48];
    }
    { // stage first row
      int sg = (d==0)? (cx*Sc+sp0) : (SLEN-1 - cx*Sc - sp0);
      if (tid < 64){
        int id0 = idsb[sg];
        float4 xv = ((const float4*)embed)[(long)id0*64 + tid];
        *(float4*)(src_lds + (tid>>4)*68 + (tid&15)*4) = xv;
      }
    }
    __syncthreads();
    for (int sp=sp0; sp<sp1; sp++){
      float4 xnext;
      int spn = (sp+1 < sp1) ? sp+1 : sp;
      int sgn = (d==0)? (cx*Sc+spn) : (SLEN-1 - cx*Sc - spn);
      if (tid < 64){
        int idn = idsb[sgn];
        xnext = ((const float4*)embed)[(long)idn*64 + tid];
      }
      float a0,a1,a2,a3;
      gemv4(w, src_lds + q*68, a0,a1,a2,a3);
      a0 = quadsum(a0); a1 = quadsum(a1); a2 = quadsum(a2); a3 = quadsum(a3);
      if (q==0){
        int nb = wave*64 + g;
        gates_lds[nb]    = a0+bb0; gates_lds[nb+16] = a1+bb1;
        gates_lds[nb+32] = a2+bb2; gates_lds[nb+48] = a3+bb3;
      }
      __syncthreads();
      xgw[(long)sp*65536 + b*1024 + tid] = gates_lds[tid];
      if (tid < 64) *(float4*)(src_lds + (tid>>4)*68 + (tid&15)*4) = xnext;
      __syncthreads();
    }
  }

  if (do_feats){
    const float* hsr = hs + ((long)(cf&1))*hs_str + (long)d*Sc*16384;
    if (wave < 9){
      float wo0 = wout[wave*512 + d*256 + lane*4+0];
      float wo1 = wout[wave*512 + d*256 + lane*4+1];
      float wo2 = wout[wave*512 + d*256 + lane*4+2];
      float wo3 = wout[wave*512 + d*256 + lane*4+3];
      for (int sp=0; sp<Sc; sp++){
        int sg = (d==0)? (cf*Sc+sp) : (SLEN-1 - cf*Sc - sp);
        float4 hv = *(const float4*)(hsr + (long)sp*16384 + b*256 + lane*4);
        float p = fmaf(hv.x,wo0, fmaf(hv.y,wo1, fmaf(hv.z,wo2, hv.w*wo3)));
        #pragma unroll
        for (int off=1; off<64; off<<=1) p += __shfl_xor(p, off);
        if (lane==0) atomicAdd(&feats[((long)sg*64 + b)*9 + wave], p);
      }
    }
  }
}

__global__ __launch_bounds__(64) void viterbi_k(
    const int* __restrict__ ids, const float* __restrict__ feats,
    const float* __restrict__ bout, const float* __restrict__ trans,
    int* __restrict__ outp)
{
  __shared__ float fl[SLEN*NTAG + 64];
  __shared__ unsigned char bps[SLEN*NTAG];
  __shared__ unsigned char mk[SLEN];
  const int b = blockIdx.x, lane = threadIdx.x;
  for (int i=lane; i<SLEN; i+=64) mk[i] = (ids[b*SLEN+i] != 0) ? 1 : 0;
  for (int i=lane; i<SLEN*NTAG; i+=64){
    int s = i/9; int t = i - s*9;
    fl[i] = feats[((long)s*64+b)*9 + t] + bout[t];
  }
  fl[SLEN*NTAG + lane] = 0.f;  // pad so lanes>=9 read in-bounds garbage
  __syncthreads();

  float Tc[9], v[9], vown;
  #pragma unroll
  for (int i=0;i<9;i++) Tc[i] = (lane<9)? trans[i*9 + lane] : 0.f;
  #pragma unroll
  for (int i=0;i<9;i++) v[i] = (i==0)?0.f:NEGV;
  vown = (lane==0)?0.f:NEGV;

  for (int s=0;s<SLEN;s++){
    float best = v[0] + Tc[0]; int bi = 0;
    #pragma unroll
    for (int i=1;i<9;i++){
      float sc = v[i] + Tc[i];
      if (sc > best){ best = sc; bi = i; }   // first-max tie-break, as jnp.argmax
    }
    float nv = best + fl[s*9 + lane];
    bool m = mk[s] != 0;
    if (m && lane<9) vown = nv;               // frozen where masked
    if (lane < 9) bps[s*9+lane] = (unsigned char)bi;
    #pragma unroll
    for (int i=0;i<9;i++) v[i] = __shfl(vown, i);
  }
  if (lane == 0){
    float best = v[0]; int tag = 0;
    #pragma unroll
    for (int i=1;i<9;i++) if (v[i] > best){ best=v[i]; tag=i; }
    outp[b*SLEN + SLEN-1] = tag;
    for (int t=SLEN-1; t>=1; t--){
      int pv = bps[t*9 + tag];
      if (!mk[t]) pv = 0;
      outp[b*SLEN + t-1] = pv;
      tag = pv;
    }
  }
}

extern "C" void kernel_launch(void* const* d_in, const int* in_sizes, int n_in,
                              void* d_out, int out_size, void* d_ws, size_t ws_size,
                              hipStream_t stream){
  (void)in_sizes; (void)n_in; (void)out_size;
  const int*   ids   = (const int*)  d_in[0];
  // d_in[1] attention_mask: unused (mask == (input_ids != 0) by construction)
  const float* embed = (const float*)d_in[2];
  const float* Wih_f = (const float*)d_in[3];
  const float* Whh_f = (const float*)d_in[4];
  const float* b_f   = (const float*)d_in[5];
  const float* Wih_r = (const float*)d_in[6];
  const float* Whh_r = (const float*)d_in[7];
  const float* b_r   = (const float*)d_in[8];
  const float* Wout  = (const float*)d_in[9];
  const float* bout  = (const float*)d_in[10];
  const float* trans = (const float*)d_in[11];

  char* ws = (char*)d_ws;
  float* wswz = (float*)ws;
  size_t off = 4ull*MSZ*4;
  float* feats = (float*)(ws+off); off += (size_t)SLEN*64*9*4;
  float* st_h  = (float*)(ws+off); off += 2ull*64*256*4;
  float* st_c  = (float*)(ws+off); off += 2ull*64*256*4;
  size_t fixed = off;

  const int cands[8] = {128,64,32,16,8,4,2,1};
  int Sc = 1;
  for (int ci=0; ci<8; ci++){
    size_t need = fixed + 2ull*2*cands[ci]*64*1024*4 + 2ull*2*cands[ci]*64*256*4;
    if (need <= ws_size){ Sc = cands[ci]; break; }
  }
  long xg_str = 2l*Sc*64*1024;
  long hs_str = 2l*Sc*64*256;
  float* xgp = (float*)(ws+fixed);
  float* hsp = xgp + 2*xg_str;
  int C = SLEN/Sc;

  hipMemsetAsync(feats, 0, (size_t)SLEN*64*9*4, stream);
  hipMemsetAsync(st_h,  0, 2ull*2*64*256*4, stream);   // st_h + st_c contiguous
  prep_swz<<<512,256,0,stream>>>(Wih_f, Whh_f, Wih_r, Whh_r, wswz);
  for (int L_=0; L_<=C+1; L_++){
    bilstm_main<<<256,1024,0,stream>>>(L_, C, Sc, ids, embed, wswz, b_f, b_r, Wout,
                                       xgp, xg_str, hsp, hs_str, feats, st_h, st_c);
  }
  viterbi_k<<<64,64,0,stream>>>(ids, feats, bout, trans, (int*)d_out);
}

// Round 2
// 13245.436 us; speedup vs baseline: 1.0002x; 1.0002x over previous
//
#include <hip/hip_runtime.h>

// BiLSTM-CRF, f32-faithful. Recurrence = 128 independent (batch,dir) chains,
// one 1024-thread wg each, Whh resident in 256 VGPRs/thread, 2-level DPP quad
// reduce; xproj pipelined on the other 128 CUs; Viterbi per-batch single-wave
// scan with bps in LDS.
//
// R1 fix: __launch_bounds__(1024, 4) — round 0 compiled at VGPR_Count=64
// (compiler chased 8 waves/SIMD occupancy) and spilled the w[4][64] weight
// array to scratch: 10 GB FETCH_SIZE/dispatch, 3.66 TB/s, VALUBusy 8%.
// 4 min-waves/EU = 1 block/CU = 512-VGPR cap -> weights stay in registers.

#define SLEN 512
#define NTAG 9
#define NEGV -10000.0f
#define MSZ (1024*256)

__device__ __forceinline__ float sigmf(float x){ return 1.0f/(1.0f+expf(-x)); }

// sum over the 4-lane quad (all 4 lanes receive the total)
__device__ __forceinline__ float quadsum(float v){
  int t = __builtin_amdgcn_update_dpp(0, __float_as_int(v), 0xB1, 0xF, 0xF, false); // quad_perm [1,0,3,2]
  v += __int_as_float(t);
  t = __builtin_amdgcn_update_dpp(0, __float_as_int(v), 0x4E, 0xF, 0xF, false);     // quad_perm [2,3,0,1]
  return v + __int_as_float(t);
}

// per-lane partial gemv: lane owns k-quarter q (64 k's), 4 gates (passes)
__device__ __forceinline__ void gemv4(const float (&w)[4][64], const float* __restrict__ sq,
                                      float &a0, float &a1, float &a2, float &a3){
  a0=0.f; a1=0.f; a2=0.f; a3=0.f;
  #pragma unroll
  for (int i=0;i<16;i++){
    float4 hv = *(const float4*)(sq + i*4);
    a0 = fmaf(hv.x, w[0][i*4+0], a0); a0 = fmaf(hv.y, w[0][i*4+1], a0);
    a0 = fmaf(hv.z, w[0][i*4+2], a0); a0 = fmaf(hv.w, w[0][i*4+3], a0);
    a1 = fmaf(hv.x, w[1][i*4+0], a1); a1 = fmaf(hv.y, w[1][i*4+1], a1);
    a1 = fmaf(hv.z, w[1][i*4+2], a1); a1 = fmaf(hv.w, w[1][i*4+3], a1);
    a2 = fmaf(hv.x, w[2][i*4+0], a2); a2 = fmaf(hv.y, w[2][i*4+1], a2);
    a2 = fmaf(hv.z, w[2][i*4+2], a2); a2 = fmaf(hv.w, w[2][i*4+3], a2);
    a3 = fmaf(hv.x, w[3][i*4+0], a3); a3 = fmaf(hv.y, w[3][i*4+1], a3);
    a3 = fmaf(hv.z, w[3][i*4+2], a3); a3 = fmaf(hv.w, w[3][i*4+3], a3);
  }
}

// Swizzle W [1024][256] so the per-lane weight loads are coalesced dwordx4.
// wswz layout (per matrix): idx = (((wave*4+p)*16+i)*64 + lane)*4 + e
//   -> W[n][k], n = wave*64+p*16+(lane>>2), k = (lane&3)*64 + i*4 + e
__global__ void prep_swz(const float* __restrict__ wih_f, const float* __restrict__ whh_f,
                         const float* __restrict__ wih_r, const float* __restrict__ whh_r,
                         float* __restrict__ out){
  for (long idx = blockIdx.x*(long)blockDim.x + threadIdx.x; idx < 4l*MSZ;
       idx += (long)gridDim.x*blockDim.x){
    int m = (int)(idx >> 18);
    int o = (int)(idx & (MSZ-1));
    int e = o & 3, L = (o>>2)&63, i = (o>>8)&15, p = (o>>12)&3, w = o>>14;
    int n = w*64 + p*16 + (L>>2);
    int k = (L&3)*64 + i*4 + e;
    const float* s = (m==0)?wih_f:(m==1)?wih_r:(m==2)?whh_f:whh_r;
    out[idx] = s[n*256 + k];
  }
}

// Roles per launch Lx (chunk size Sc, C = 512/Sc chunks):
//   Lx==0            : all 256 wgs do xproj(chunk 0), split halves
//   Lx in [1..C+1]   : wg<128 -> recurrence(chunk Lx-1) ; wg>=128 -> xproj(Lx) + feats(Lx-2)
__global__ __launch_bounds__(1024, 4) void bilstm_main(
    int Lx, int C, int Sc,
    const int*   __restrict__ ids,     // [64][512]
    const float* __restrict__ embed,   // [V][256]
    const float* __restrict__ wswz,    // [role*2+dir][1024*256]  role0=Wih,1=Whh
    const float* __restrict__ bias_f, const float* __restrict__ bias_r,
    const float* __restrict__ wout,    // [9][512]
    float* __restrict__ xg, long xg_str,   // dbuf [2][2][Sc][64][1024]
    float* __restrict__ hs, long hs_str,   // dbuf [2][2][Sc][64][256]
    float* __restrict__ feats,             // [512][64][9]
    float* __restrict__ st_h, float* __restrict__ st_c) // [2][64][256]
{
  __shared__ float src_lds[4*68];     // h or x, quarter-padded (bank-conflict-free)
  __shared__ float gates_lds[1024];

  const int tid = threadIdx.x;
  const int wave = tid>>6, lane = tid&63, q = lane&3, g = lane>>2;
  const int wgid = blockIdx.x;

  bool do_recur=false, do_xproj=false, do_feats=false;
  int d=0, b=0, sp0=0, sp1=Sc, cr=0, cx=0, cf=-1;
  if (Lx == 0){
    d = (wgid>>6)&1; b = wgid&63;
    do_xproj = true; cx = 0;
    sp0 = (wgid>>7) ? (Sc/2) : 0;
    sp1 = (wgid>>7) ? Sc : (Sc/2);
  } else if (wgid < 128){
    d = wgid>>6; b = wgid&63;
    cr = Lx-1; do_recur = (cr < C);
  } else {
    int w2 = wgid-128; d = w2>>6; b = w2&63;
    cx = Lx; do_xproj = (cx < C);
    cf = Lx-2; do_feats = (cf >= 0 && cf < C);
  }

  float w[4][64];   // 256 VGPRs of resident weights (static-indexed only!)
  if (do_recur || do_xproj){
    int role = do_recur ? 1 : 0;
    const float4* wp = (const float4*)(wswz + (long)(role*2 + d)*MSZ);
    #pragma unroll
    for (int p=0;p<4;p++){
      #pragma unroll
      for (int i=0;i<16;i++){
        float4 v = wp[((wave*4+p)*16 + i)*64 + lane];
        w[p][i*4+0]=v.x; w[p][i*4+1]=v.y; w[p][i*4+2]=v.z; w[p][i*4+3]=v.w;
      }
    }
  }

  if (do_recur){
    const float* xgr = xg + ((long)(cr&1))*xg_str + (long)d*Sc*65536;
    float*       hsw = hs + ((long)(cr&1))*hs_str + (long)d*Sc*16384;
    const int*  idsb = ids + b*SLEN;
    float h_reg=0.f, c_reg=0.f;
    if (tid < 256){
      h_reg = st_h[(d*64+b)*256 + tid];
      c_reg = st_c[(d*64+b)*256 + tid];
      src_lds[(tid>>6)*68 + (tid&63)] = h_reg;
    }
    __syncthreads();
    for (int sp=0; sp<Sc; sp++){
      const int sg = (d==0) ? (cr*Sc + sp) : (SLEN-1 - cr*Sc - sp);
      float xgi=0,xgf=0,xgg=0,xgo=0; int idv=0;
      if (tid < 256){
        const float* xr = xgr + (long)sp*65536 + b*1024 + tid;
        xgi = xr[0]; xgf = xr[256]; xgg = xr[512]; xgo = xr[768];
        idv = idsb[sg];                  // mask == (id != 0) by construction
      }
      float a0,a1,a2,a3;
      gemv4(w, src_lds + q*68, a0,a1,a2,a3);
      a0 = quadsum(a0); a1 = quadsum(a1); a2 = quadsum(a2); a3 = quadsum(a3);
      if (q == 0){
        int nb = wave*64 + g;
        gates_lds[nb]    = a0; gates_lds[nb+16] = a1;
        gates_lds[nb+32] = a2; gates_lds[nb+48] = a3;
      }
      __syncthreads();
      if (tid < 256){
        float pi = xgi + gates_lds[tid];
        float pf = xgf + gates_lds[256+tid];
        float pg = xgg + gates_lds[512+tid];
        float po = xgo + gates_lds[768+tid];
        float ii=sigmf(pi), ff=sigmf(pf), gv=tanhf(pg), oo=sigmf(po);
        float cn = ff*c_reg + ii*gv;
        float hn = oo*tanhf(cn);
        if (idv != 0){ c_reg = cn; h_reg = hn; }     // freeze on masked steps
        src_lds[(tid>>6)*68 + (tid&63)] = h_reg;
        hsw[(long)sp*16384 + b*256 + tid] = h_reg;
      }
      __syncthreads();
    }
    if (tid < 256){
      st_h[(d*64+b)*256+tid] = h_reg;
      st_c[(d*64+b)*256+tid] = c_reg;
    }
  }

  if (do_xproj){
    float*      xgw = xg + ((long)(cx&1))*xg_str + (long)d*Sc*65536;
    const int* idsb = ids + b*SLEN;
    const float* bptr = (d==0)? bias_f : bias_r;
    float bb0=0,bb1=0,bb2=0,bb3=0;
    if (q==0){
      int nb = wave*64 + g;
      bb0=bptr[nb]; bb1=bptr[nb+16]; bb2=bptr[nb+32]; bb3=bptr[nb+48];
    }
    { // stage first row
      int sg = (d==0)? (cx*Sc+sp0) : (SLEN-1 - cx*Sc - sp0);
      if (tid < 64){
        int id0 = idsb[sg];
        float4 xv = ((const float4*)embed)[(long)id0*64 + tid];
        *(float4*)(src_lds + (tid>>4)*68 + (tid&15)*4) = xv;
      }
    }
    __syncthreads();
    for (int sp=sp0; sp<sp1; sp++){
      float4 xnext;
      int spn = (sp+1 < sp1) ? sp+1 : sp;
      int sgn = (d==0)? (cx*Sc+spn) : (SLEN-1 - cx*Sc - spn);
      if (tid < 64){
        int idn = idsb[sgn];
        xnext = ((const float4*)embed)[(long)idn*64 + tid];
      }
      float a0,a1,a2,a3;
      gemv4(w, src_lds + q*68, a0,a1,a2,a3);
      a0 = quadsum(a0); a1 = quadsum(a1); a2 = quadsum(a2); a3 = quadsum(a3);
      if (q==0){
        int nb = wave*64 + g;
        gates_lds[nb]    = a0+bb0; gates_lds[nb+16] = a1+bb1;
        gates_lds[nb+32] = a2+bb2; gates_lds[nb+48] = a3+bb3;
      }
      __syncthreads();
      xgw[(long)sp*65536 + b*1024 + tid] = gates_lds[tid];
      if (tid < 64) *(float4*)(src_lds + (tid>>4)*68 + (tid&15)*4) = xnext;
      __syncthreads();
    }
  }

  if (do_feats){
    const float* hsr = hs + ((long)(cf&1))*hs_str + (long)d*Sc*16384;
    if (wave < 9){
      float wo0 = wout[wave*512 + d*256 + lane*4+0];
      float wo1 = wout[wave*512 + d*256 + lane*4+1];
      float wo2 = wout[wave*512 + d*256 + lane*4+2];
      float wo3 = wout[wave*512 + d*256 + lane*4+3];
      for (int sp=0; sp<Sc; sp++){
        int sg = (d==0)? (cf*Sc+sp) : (SLEN-1 - cf*Sc - sp);
        float4 hv = *(const float4*)(hsr + (long)sp*16384 + b*256 + lane*4);
        float p = fmaf(hv.x,wo0, fmaf(hv.y,wo1, fmaf(hv.z,wo2, hv.w*wo3)));
        #pragma unroll
        for (int off=1; off<64; off<<=1) p += __shfl_xor(p, off);
        if (lane==0) atomicAdd(&feats[((long)sg*64 + b)*9 + wave], p);
      }
    }
  }
}

__global__ __launch_bounds__(64) void viterbi_k(
    const int* __restrict__ ids, const float* __restrict__ feats,
    const float* __restrict__ bout, const float* __restrict__ trans,
    int* __restrict__ outp)
{
  __shared__ float fl[SLEN*NTAG + 64];
  __shared__ unsigned char bps[SLEN*NTAG];
  __shared__ unsigned char mk[SLEN];
  const int b = blockIdx.x, lane = threadIdx.x;
  for (int i=lane; i<SLEN; i+=64) mk[i] = (ids[b*SLEN+i] != 0) ? 1 : 0;
  for (int i=lane; i<SLEN*NTAG; i+=64){
    int s = i/9; int t = i - s*9;
    fl[i] = feats[((long)s*64+b)*9 + t] + bout[t];
  }
  fl[SLEN*NTAG + lane] = 0.f;  // pad so lanes>=9 read in-bounds garbage
  __syncthreads();

  float Tc[9], v[9], vown;
  #pragma unroll
  for (int i=0;i<9;i++) Tc[i] = (lane<9)? trans[i*9 + lane] : 0.f;
  #pragma unroll
  for (int i=0;i<9;i++) v[i] = (i==0)?0.f:NEGV;
  vown = (lane==0)?0.f:NEGV;

  for (int s=0;s<SLEN;s++){
    float best = v[0] + Tc[0]; int bi = 0;
    #pragma unroll
    for (int i=1;i<9;i++){
      float sc = v[i] + Tc[i];
      if (sc > best){ best = sc; bi = i; }   // first-max tie-break, as jnp.argmax
    }
    float nv = best + fl[s*9 + lane];
    bool m = mk[s] != 0;
    if (m && lane<9) vown = nv;               // frozen where masked
    if (lane < 9) bps[s*9+lane] = (unsigned char)bi;
    #pragma unroll
    for (int i=0;i<9;i++) v[i] = __shfl(vown, i);
  }
  if (lane == 0){
    float best = v[0]; int tag = 0;
    #pragma unroll
    for (int i=1;i<9;i++) if (v[i] > best){ best=v[i]; tag=i; }
    outp[b*SLEN + SLEN-1] = tag;
    for (int t=SLEN-1; t>=1; t--){
      int pv = bps[t*9 + tag];
      if (!mk[t]) pv = 0;
      outp[b*SLEN + t-1] = pv;
      tag = pv;
    }
  }
}

extern "C" void kernel_launch(void* const* d_in, const int* in_sizes, int n_in,
                              void* d_out, int out_size, void* d_ws, size_t ws_size,
                              hipStream_t stream){
  (void)in_sizes; (void)n_in; (void)out_size;
  const int*   ids   = (const int*)  d_in[0];
  // d_in[1] attention_mask: unused (mask == (input_ids != 0) by construction)
  const float* embed = (const float*)d_in[2];
  const float* Wih_f = (const float*)d_in[3];
  const float* Whh_f = (const float*)d_in[4];
  const float* b_f   = (const float*)d_in[5];
  const float* Wih_r = (const float*)d_in[6];
  const float* Whh_r = (const float*)d_in[7];
  const float* b_r   = (const float*)d_in[8];
  const float* Wout  = (const float*)d_in[9];
  const float* bout  = (const float*)d_in[10];
  const float* trans = (const float*)d_in[11];

  char* ws = (char*)d_ws;
  float* wswz = (float*)ws;
  size_t off = 4ull*MSZ*4;
  float* feats = (float*)(ws+off); off += (size_t)SLEN*64*9*4;
  float* st_h  = (float*)(ws+off); off += 2ull*64*256*4;
  float* st_c  = (float*)(ws+off); off += 2ull*64*256*4;
  size_t fixed = off;

  const int cands[8] = {128,64,32,16,8,4,2,1};
  int Sc = 1;
  for (int ci=0; ci<8; ci++){
    size_t need = fixed + 2ull*2*cands[ci]*64*1024*4 + 2ull*2*cands[ci]*64*256*4;
    if (need <= ws_size){ Sc = cands[ci]; break; }
  }
  long xg_str = 2l*Sc*64*1024;
  long hs_str = 2l*Sc*64*256;
  float* xgp = (float*)(ws+fixed);
  float* hsp = xgp + 2*xg_str;
  int C = SLEN/Sc;

  hipMemsetAsync(feats, 0, (size_t)SLEN*64*9*4, stream);
  hipMemsetAsync(st_h,  0, 2ull*2*64*256*4, stream);   // st_h + st_c contiguous
  prep_swz<<<512,256,0,stream>>>(Wih_f, Whh_f, Wih_r, Whh_r, wswz);
  for (int L_=0; L_<=C+1; L_++){
    bilstm_main<<<256,1024,0,stream>>>(L_, C, Sc, ids, embed, wswz, b_f, b_r, Wout,
                                       xgp, xg_str, hsp, hs_str, feats, st_h, st_c);
  }
  viterbi_k<<<64,64,0,stream>>>(ids, feats, bout, trans, (int*)d_out);
}

// Round 3
// 6967.106 us; speedup vs baseline: 1.9015x; 1.9011x over previous
//
#include <hip/hip_runtime.h>

#define SLEN 512
#define NTAG 9
#define NEGV -10000.0f

typedef float f32x2 __attribute__((ext_vector_type(2)));
typedef float f32x4 __attribute__((ext_vector_type(4)));

__device__ __forceinline__ void pkfma(f32x2 &acc, f32x2 a, f32x2 b){
  asm("v_pk_fma_f32 %0, %1, %2, %0" : "+v"(acc) : "v"(a), "v"(b));
}
__device__ __forceinline__ float qsum(float v){
  int t = __builtin_amdgcn_update_dpp(0, __float_as_int(v), 0xB1, 0xF, 0xF, false);
  v += __int_as_float(t);
  t = __builtin_amdgcn_update_dpp(0, __float_as_int(v), 0x4E, 0xF, 0xF, false);
  return v + __int_as_float(t);
}
__device__ __forceinline__ float rsum16(float v){
  v = qsum(v);
  int t = __builtin_amdgcn_update_dpp(0, __float_as_int(v), 0x124, 0xF, 0xF, false);
  v += __int_as_float(t);
  t = __builtin_amdgcn_update_dpp(0, __float_as_int(v), 0x128, 0xF, 0xF, false);
  return v + __int_as_float(t);
}

__global__ void prep_k(const float* __restrict__ wihf, const float* __restrict__ whhf,
                       const float* __restrict__ wihr, const float* __restrict__ whhr,
                       float* __restrict__ wR, float* __restrict__ wX){
  const int n = 524288;
  for (int i = blockIdx.x*blockDim.x + threadIdx.x; i < n; i += gridDim.x*blockDim.x){
    int e = i & 3, t = (i>>2) & 1023, inst = (i>>12) & 15, q = (i>>16) & 3, d = i>>18;
    const float* whh = d ? whhr : whhf;
    wR[i] = whh[ ((inst>>2)*256 + (t>>2))*256 + q*64 + (t&3)*16 + (inst&3)*4 + e ];
    const float* wih = d ? wihr : wihf;
    wX[i] = wih[ (q*256 + (t>>4)*4 + (inst>>2))*256 + (t&15)*16 + (inst&3)*4 + e ];
  }
}

__global__ __launch_bounds__(1024, 4) void xproj_k(
    int c0, int Sc,
    const int* __restrict__ ids, const float* __restrict__ embed,
    const float* __restrict__ wX,
    const float* __restrict__ bias_f, const float* __restrict__ bias_r,
    float* __restrict__ xg)
{
  __shared__ __align__(16) float xl[4][272];
  const int t = threadIdx.x;
  const int id = blockIdx.x;
  const int bp = id & 31, rq = (id>>5) & 3, d = id>>7;
  const int ks = t & 15, rg = t>>4;

  f32x2 w[4][8];
  {
    const f32x4* wp = (const f32x4*)(wX + ((long)(d*4+rq)*16)*4096);
    #pragma unroll
    for (int inst=0; inst<16; inst++){
      f32x4 v = wp[inst*1024 + t];
      int rr = inst>>2, i4 = inst&3;
      w[rr][i4*2+0] = f32x2{v.x, v.y};
      w[rr][i4*2+1] = f32x2{v.z, v.w};
    }
  }
  f32x4 bias = {0.f,0.f,0.f,0.f};
  if (ks == 0){
    const float* bb = d ? bias_r : bias_f;
    bias = *(const f32x4*)(bb + rq*256 + rg*4);
  }
  for (int bi=0; bi<2; bi++){
    const int b = bp*2 + bi;
    const int* idsb = ids + b*SLEN;
    for (int sp0=0; sp0<Sc; sp0+=4){
      __syncthreads();
      if (t < 256){
        int tk = t>>6, l = t&63;
        int sp = sp0 + tk;
        int sg = d ? (SLEN-1 - (c0*Sc+sp)) : (c0*Sc+sp);
        f32x4 xv = ((const f32x4*)embed)[ (long)idsb[sg]*64 + l ];
        *(f32x4*)&xl[tk][l*4] = xv;
      }
      __syncthreads();
      #pragma unroll
      for (int tk=0; tk<4; tk++){
        int sp = sp0 + tk;
        f32x2 a0={0.f,0.f}, a1={0.f,0.f}, a2={0.f,0.f}, a3={0.f,0.f};
        #pragma unroll
        for (int i4=0; i4<4; i4++){
          f32x4 xv = *(const f32x4*)&xl[tk][ks*16 + i4*4];
          f32x2 lo = {xv.x, xv.y}, hi = {xv.z, xv.w};
          pkfma(a0, w[0][i4*2], lo); pkfma(a0, w[0][i4*2+1], hi);
          pkfma(a1, w[1][i4*2], lo); pkfma(a1, w[1][i4*2+1], hi);
          pkfma(a2, w[2][i4*2], lo); pkfma(a2, w[2][i4*2+1], hi);
          pkfma(a3, w[3][i4*2], lo); pkfma(a3, w[3][i4*2+1], hi);
        }
        float s0 = rsum16(a0.x + a0.y);
        float s1 = rsum16(a1.x + a1.y);
        float s2 = rsum16(a2.x + a2.y);
        float s3 = rsum16(a3.x + a3.y);
        if (ks == 0){
          f32x4 o = {s0+bias.x, s1+bias.y, s2+bias.z, s3+bias.w};
          *(f32x4*)(xg + (((long)(d*Sc + sp)*64 + b)*1024) + rq*256 + rg*4) = o;
        }
      }
    }
  }
}

__global__ __launch_bounds__(1024, 4) void recur_k(
    int c0, int Sc,
    const int* __restrict__ ids,
    const float* __restrict__ wR,
    const float* __restrict__ xg,
    float* __restrict__ hs,
    float* __restrict__ st_h, float* __restrict__ st_c,
    float* __restrict__ send, int* __restrict__ flags)
{
  __shared__ __align__(16) float hl[2][68];
  const int t = threadIdx.x;
  const int id = blockIdx.x;
  const int kq = id>>6, g6 = id&63, d = g6>>5, bp = g6&31;
  const int j = t>>2, c = t&3;
  const bool upd = (j>>6) == kq;
  const long PAR = 524288;

  f32x2 w[4][8];
  {
    const f32x4* wp = (const f32x4*)(wR + ((long)(d*4+kq)*16)*4096);
    #pragma unroll
    for (int inst=0; inst<16; inst++){
      f32x4 v = wp[inst*1024 + t];
      int g = inst>>2, i4 = inst&3;
      w[g][i4*2+0] = f32x2{v.x, v.y};
      w[g][i4*2+1] = f32x2{v.z, v.w};
    }
  }
  float cst = 0.f, hprev = 0.f;
  if (upd && c < 2){
    int b = bp*2 + c;
    hprev = st_h[(d*64+b)*256 + j];
    cst   = st_c[(d*64+b)*256 + j];
    hl[c][j & 63] = hprev;
  }
  __syncthreads();

  for (int sp=0; sp<Sc; sp++){
    const int stepg = c0*Sc + sp;
    const int par = stepg & 1;
    const int sg = d ? (SLEN-1 - stepg) : stepg;

    f32x2 a[4][2];
    #pragma unroll
    for (int g=0; g<4; g++){ a[g][0] = f32x2{0.f,0.f}; a[g][1] = f32x2{0.f,0.f}; }
    #pragma unroll
    for (int b=0; b<2; b++){
      #pragma unroll
      for (int i4=0; i4<4; i4++){
        f32x4 hv = *(const f32x4*)&hl[b][c*16 + i4*4];
        f32x2 lo = {hv.x, hv.y}, hi = {hv.z, hv.w};
        pkfma(a[0][b], w[0][i4*2], lo); pkfma(a[0][b], w[0][i4*2+1], hi);
        pkfma(a[1][b], w[1][i4*2], lo); pkfma(a[1][b], w[1][i4*2+1], hi);
        pkfma(a[2][b], w[2][i4*2], lo); pkfma(a[2][b], w[2][i4*2+1], hi);
        pkfma(a[3][b], w[3][i4*2], lo); pkfma(a[3][b], w[3][i4*2+1], hi);
      }
    }
    float p[4][2];
    #pragma unroll
    for (int g=0; g<4; g++){
      p[g][0] = qsum(a[g][0].x + a[g][0].y);
      p[g][1] = qsum(a[g][1].x + a[g][1].y);
    }
    if (!upd && c == 0){
      float* sb = send + par*PAR + ((((long)(d*32+bp)*4 + kq)*256 + j)*8);
      #pragma unroll
      for (int g=0; g<4; g++){
        __hip_atomic_store(sb + g*2 + 0, p[g][0], __ATOMIC_RELAXED, __HIP_MEMORY_SCOPE_AGENT);
        __hip_atomic_store(sb + g*2 + 1, p[g][1], __ATOMIC_RELAXED, __HIP_MEMORY_SCOPE_AGENT);
      }
    }
    __syncthreads();
    if (t == 0)
      __hip_atomic_store(&flags[(d*32+bp)*4 + kq], stepg+1, __ATOMIC_RELEASE, __HIP_MEMORY_SCOPE_AGENT);
    if (t < 3){
      int src = (kq + 1 + t) & 3;
      int cnt = 0;
      while (__hip_atomic_load(&flags[(d*32+bp)*4 + src], __ATOMIC_ACQUIRE, __HIP_MEMORY_SCOPE_AGENT) < stepg+1){
        if (++cnt > (1<<22)) break;
      }
    }
    __syncthreads();
    if (upd && c < 2){
      const int b = bp*2 + c;
      float tot0 = p[0][c], tot1 = p[1][c], tot2 = p[2][c], tot3 = p[3][c];
      #pragma unroll
      for (int s3=1; s3<4; s3++){
        int src = (kq + s3) & 3;
        const float* rb = send + par*PAR + ((((long)(d*32+bp)*4 + src)*256 + j)*8);
        tot0 += __hip_atomic_load(rb + 0 + c, __ATOMIC_RELAXED, __HIP_MEMORY_SCOPE_AGENT);
        tot1 += __hip_atomic_load(rb + 2 + c, __ATOMIC_RELAXED, __HIP_MEMORY_SCOPE_AGENT);
        tot2 += __hip_atomic_load(rb + 4 + c, __ATOMIC_RELAXED, __HIP_MEMORY_SCOPE_AGENT);
        tot3 += __hip_atomic_load(rb + 6 + c, __ATOMIC_RELAXED, __HIP_MEMORY_SCOPE_AGENT);
      }
      const float* xr = xg + (((long)(d*Sc + sp)*64 + b)*1024) + j;
      float pi = tot0 + xr[0];
      float pf = tot1 + xr[256];
      float pg = tot2 + xr[512];
      float po = tot3 + xr[768];
      float ii = 1.f/(1.f+expf(-pi)), ff = 1.f/(1.f+expf(-pf));
      float gv = tanhf(pg), oo = 1.f/(1.f+expf(-po));
      float cn = ff*cst + ii*gv;
      float hn = oo*tanhf(cn);
      if (ids[b*SLEN + sg] != 0){ cst = cn; hprev = hn; }
      hl[c][j & 63] = hprev;
      hs[((long)sg*64 + b)*512 + d*256 + j] = hprev;
    }
    __syncthreads();
  }
  if (upd && c < 2){
    int b = bp*2 + c;
    st_h[(d*64+b)*256 + j] = hprev;
    st_c[(d*64+b)*256 + j] = cst;
  }
}

__global__ __launch_bounds__(576) void feats_k(
    const float* __restrict__ hs, const float* __restrict__ wout,
    float* __restrict__ feats)
{
  __shared__ __align__(16) float hlds[64*512];
  __shared__ __align__(16) float wl[NTAG*512];
  const int s = blockIdx.x, t = threadIdx.x;
  for (int i = t; i < 64*512/4; i += 576)
    ((f32x4*)hlds)[i] = ((const f32x4*)(hs + (long)s*64*512))[i];
  for (int i = t; i < NTAG*512/4; i += 576)
    ((f32x4*)wl)[i] = ((const f32x4*)wout)[i];
  __syncthreads();
  int b = t / 9, tag = t - b*9;
  float acc = 0.f;
  const float* hb = hlds + b*512;
  const float* wb = wl + tag*512;
  for (int k=0; k<512; k+=4){
    f32x4 h4 = *(const f32x4*)(hb+k);
    f32x4 w4 = *(const f32x4*)(wb+k);
    acc += h4.x*w4.x + h4.y*w4.y + h4.z*w4.z + h4.w*w4.w;
  }
  feats[((long)s*64 + b)*9 + tag] = acc;
}

__global__ __launch_bounds__(64) void viterbi_k(
    const int* __restrict__ ids, const float* __restrict__ feats,
    const float* __restrict__ bout, const float* __restrict__ trans,
    int* __restrict__ outp)
{
  __shared__ float fl[SLEN*NTAG + 64];
  __shared__ unsigned char bps[SLEN*NTAG];
  __shared__ unsigned char mk[SLEN];
  const int b = blockIdx.x, lane = threadIdx.x;
  for (int i=lane; i<SLEN; i+=64) mk[i] = (ids[b*SLEN+i] != 0) ? 1 : 0;
  for (int i=lane; i<SLEN*NTAG; i+=64){
    int s = i/9; int t = i - s*9;
    fl[i] = feats[((long)s*64+b)*9 + t] + bout[t];
  }
  fl[SLEN*NTAG + lane] = 0.f;
  __syncthreads();

  float Tc[9], v[9], vown;
  #pragma unroll
  for (int i=0;i<9;i++) Tc[i] = (lane<9)? trans[i*9 + lane] : 0.f;
  #pragma unroll
  for (int i=0;i<9;i++) v[i] = (i==0)?0.f:NEGV;
  vown = (lane==0)?0.f:NEGV;

  for (int s=0;s<SLEN;s++){
    float best = v[0] + Tc[0]; int bi = 0;
    #pragma unroll
    for (int i=1;i<9;i++){
      float sc = v[i] + Tc[i];
      if (sc > best){ best = sc; bi = i; }
    }
    float nv = best + fl[s*9 + lane];
    bool m = mk[s] != 0;
    if (m && lane<9) vown = nv;
    if (lane < 9) bps[s*9+lane] = (unsigned char)bi;
    #pragma unroll
    for (int i=0;i<9;i++) v[i] = __shfl(vown, i);
  }
  if (lane == 0){
    float best = v[0]; int tag = 0;
    #pragma unroll
    for (int i=1;i<9;i++) if (v[i] > best){ best=v[i]; tag=i; }
    outp[b*SLEN + SLEN-1] = tag;
    for (int t=SLEN-1; t>=1; t--){
      int pv = bps[t*9 + tag];
      if (!mk[t]) pv = 0;
      outp[b*SLEN + t-1] = pv;
      tag = pv;
    }
  }
}

extern "C" void kernel_launch(void* const* d_in, const int* in_sizes, int n_in,
                              void* d_out, int out_size, void* d_ws, size_t ws_size,
                              hipStream_t stream){
  (void)in_sizes; (void)n_in; (void)out_size;
  const int*   ids   = (const int*)  d_in[0];
  const float* embed = (const float*)d_in[2];
  const float* Wih_f = (const float*)d_in[3];
  const float* Whh_f = (const float*)d_in[4];
  const float* b_f   = (const float*)d_in[5];
  const float* Wih_r = (const float*)d_in[6];
  const float* Whh_r = (const float*)d_in[7];
  const float* b_r   = (const float*)d_in[8];
  const float* Wout  = (const float*)d_in[9];
  const float* bout  = (const float*)d_in[10];
  const float* trans = (const float*)d_in[11];

  float* fw = (float*)d_ws;
  size_t off = 0;
  float* wR    = fw + off; off += 524288;
  float* wX    = fw + off; off += 524288;
  float* send  = fw + off; off += 1048576;
  float* st_h  = fw + off; off += 32768;
  float* st_c  = fw + off; off += 32768;
  float* hs    = fw + off; off += 16777216;
  float* featb = fw + off; off += 294912;      // 512*64*9
  int*   flags = (int*)(fw + off); off += 1024;
  float* xg    = fw + off;
  size_t fixedB = off*4;

  const int cands[7] = {512,256,128,64,32,16,8};
  int Sc = 8;
  for (int ci=0; ci<7; ci++){
    size_t need = fixedB + (size_t)cands[ci]*131072*4;
    if (need <= ws_size){ Sc = cands[ci]; break; }
  }
  const int C = SLEN / Sc;

  hipMemsetAsync(flags, 0, 1024*4, stream);
  hipMemsetAsync(st_h, 0, 2*32768*4, stream);
  prep_k<<<256,256,0,stream>>>(Wih_f, Whh_f, Wih_r, Whh_r, wR, wX);
  for (int c0=0; c0<C; c0++){
    xproj_k<<<256,1024,0,stream>>>(c0, Sc, ids, embed, wX, b_f, b_r, xg);
    recur_k<<<256,1024,0,stream>>>(c0, Sc, ids, wR, xg, hs, st_h, st_c, send, flags);
  }
  feats_k<<<512,576,0,stream>>>(hs, Wout, featb);
  viterbi_k<<<64,64,0,stream>>>(ids, featb, bout, trans, (int*)d_out);
}